// Round 5
// baseline (35.204 us; speedup 1.0000x reference)
//
#include <hip/hip_runtime.h>
#include <hip/hip_bf16.h>

// out[i] = a[i, argmax_j(z[i, 3+j])], j in {0,1,2}, first-max tie-break.
// B = 4194304 rows; z row = 8 f32 (32B), a row = 3 f32 (12B).
//
// Barrier-free, LDS-free: one wave handles 64 rows.
//  - z: lane l loads one contiguous float4 (lane pair = one row). 3 word swaps
//    via shfl_xor(1) give every lane its row's colors; all lanes compute argmax.
//  - a: per-lane dword gather a[row*3+j] (lane pairs share address, 384B/wave).
//  - out: two shfl's permute results into lane order -> coalesced dword store.

#define NTHREADS 256

typedef float nfloat4 __attribute__((ext_vector_type(4)));

__global__ __launch_bounds__(NTHREADS) void color_val_shfl(
    const float* __restrict__ z,
    const float* __restrict__ a,
    float* __restrict__ out,
    size_t nwaves)  // = B/64
{
    const int lane = threadIdx.x & 63;
    const size_t wave = ((size_t)blockIdx.x * (NTHREADS / 64)) + (threadIdx.x >> 6);
    if (wave >= nwaves) return;

    const size_t R0 = wave * 64;  // first row of this wave's chunk
    const nfloat4* zg = reinterpret_cast<const nfloat4*>(z) + R0 * 2;

    float res[2];  // res[0]: a-value for round-A row, res[1]: round-B row
#pragma unroll
    for (int rd = 0; rd < 2; ++rd) {
        nfloat4 v = __builtin_nontemporal_load(&zg[rd * 64 + lane]);
        // lane pair (2k,2k+1) covers row k: even lane = elems 0-3, odd = 4-7
        float o0 = __shfl_xor(v[0], 1);  // partner's elem4 (for even lanes)
        float o1 = __shfl_xor(v[1], 1);  // partner's elem5 (for even lanes)
        float o3 = __shfl_xor(v[3], 1);  // partner's elem3 (for odd lanes)
        bool odd = lane & 1;
        float c0 = odd ? o3 : v[3];
        float c1 = odd ? v[0] : o0;
        float c2 = odd ? v[1] : o1;
        int j = 0;
        float m = c0;
        if (c1 > m) { m = c1; j = 1; }   // strict > => first-max tie-break
        if (c2 > m) {          j = 2; }
        size_t row = R0 + (size_t)rd * 32 + (lane >> 1);
        res[rd] = a[row * 3 + j];        // pairs share address; 384B per wave
    }

    // lane l wants row R0+l: round A result lives on lane 2l (l<32),
    // round B result on lane 2(l-32) (l>=32).
    int src = (2 * lane) & 63;
    float rA = __shfl(res[0], src);
    float rB = __shfl(res[1], src);
    float r = (lane < 32) ? rA : rB;
    __builtin_nontemporal_store(r, &out[R0 + lane]);  // coalesced dword store
}

// generic tail (unused for B=4194304, kept for safety)
__global__ void color_val_tail(
    const float* __restrict__ z,
    const float* __restrict__ a,
    float* __restrict__ out,
    size_t start, size_t B)
{
    size_t i = start + blockIdx.x * blockDim.x + threadIdx.x;
    if (i >= B) return;
    float c0 = z[i * 8 + 3], c1 = z[i * 8 + 4], c2 = z[i * 8 + 5];
    float val = a[i * 3 + 0];
    float m = c0;
    if (c1 > m) { m = c1; val = a[i * 3 + 1]; }
    if (c2 > m) {          val = a[i * 3 + 2]; }
    out[i] = val;
}

extern "C" void kernel_launch(void* const* d_in, const int* in_sizes, int n_in,
                              void* d_out, int out_size, void* d_ws, size_t ws_size,
                              hipStream_t stream) {
    const float* z = (const float*)d_in[0];  // (B, 8) f32
    const float* a = (const float*)d_in[1];  // (B, 3) f32
    float* out = (float*)d_out;              // (B,)  f32

    size_t B = (size_t)out_size;             // 4194304
    size_t nwaves = B / 64;                  // 65536
    size_t rem = B % 64;                     // 0

    if (nwaves > 0) {
        int wavesPerBlock = NTHREADS / 64;
        int blocks = (int)((nwaves + wavesPerBlock - 1) / wavesPerBlock);
        color_val_shfl<<<blocks, NTHREADS, 0, stream>>>(z, a, out, nwaves);
    }
    if (rem > 0) {
        size_t start = nwaves * 64;
        int blocks = (int)((rem + 255) / 256);
        color_val_tail<<<blocks, 256, 0, stream>>>(z, a, out, start, B);
    }
}